// Round 8
// baseline (114.385 us; speedup 1.0000x reference)
//
#include <hip/hip_runtime.h>
#include <hip/hip_bf16.h>

// Problem constants
#define BB 128        // batch
#define NN 100000     // memory bank size
#define DD 256        // feat dim (K)
#define CC 2000       // num classes
#define SS 751        // source classes
#define INVTEMP 20.0f // 1/0.05
#define EPSV 1e-6f

#define HIST_BLOCKS 391   // ceil(100000/256)
#define PREP_BLOCKS 32    // 8192/256
#define GPERS 512         // persistent grid: 2 blocks/CU co-resident

typedef __attribute__((ext_vector_type(8))) short bf16x8;   // 8 bf16 in 4 VGPRs
typedef __attribute__((ext_vector_type(8))) unsigned short u16x8;
typedef __attribute__((ext_vector_type(4))) float f32x4;

__device__ __forceinline__ unsigned short f2bf(float x) {
    unsigned int u = __float_as_uint(x);
    u += 0x7fffu + ((u >> 16) & 1u);   // round-to-nearest-even
    return (unsigned short)(u >> 16);
}

__device__ __forceinline__ u16x8 pack8(float4 a, float4 b) {
    u16x8 o;
    o[0] = f2bf(a.x); o[1] = f2bf(a.y); o[2] = f2bf(a.z); o[3] = f2bf(a.w);
    o[4] = f2bf(b.x); o[5] = f2bf(b.y); o[6] = f2bf(b.z); o[7] = f2bf(b.w);
    return o;
}

// ---------------- fused: histogram + input-fragment prep ----------------
// inb layout: 16B chunk ch = (nr*8 + kc)*64 + l holds
//   row = nr*16 + (l&15)  (rows 0..127 inputs, 128..255 inputs2)
//   k   = kc*32 + (l>>4)*8 + j, j=0..7
__global__ __launch_bounds__(256) void hist_prep_kernel(
    const int* __restrict__ labels, int* __restrict__ counts,
    const float* __restrict__ in1, const float* __restrict__ in2,
    unsigned short* __restrict__ inb)
{
    int bid = blockIdx.x;
    if (bid < HIST_BLOCKS) {
        int n = bid * 256 + threadIdx.x;
        if (n < NN) atomicAdd(&counts[labels[n]], 1);
    } else {
        int ch = (bid - HIST_BLOCKS) * 256 + threadIdx.x;
        if (ch >= 8192) return;
        int l  = ch & 63;
        int kc = (ch >> 6) & 7;
        int nr = ch >> 9;
        int row = nr * 16 + (l & 15);
        const float* src = (row < BB) ? (in1 + (size_t)row * DD)
                                      : (in2 + (size_t)(row - BB) * DD);
        int k0 = kc * 32 + ((l >> 4) << 3);
        u16x8 o;
        #pragma unroll
        for (int j = 0; j < 8; ++j) o[j] = f2bf(src[k0 + j]);
        *(u16x8*)(inb + (size_t)ch * 8) = o;
    }
}

// one block, 256 threads, exclusive scan over 2048 (padded) counts; also zeroes out
__global__ __launch_bounds__(256) void scan_kernel(const int* __restrict__ counts,
                                                   int* __restrict__ offsets,
                                                   int* __restrict__ cursor,
                                                   float* __restrict__ out) {
    const int PT = 8; // 256*8 = 2048 >= CC
    int tid = threadIdx.x;
    if (tid == 0) { out[0] = 0.f; out[1] = 0.f; }
    int vals[PT];
    int tot = 0;
    #pragma unroll
    for (int i = 0; i < PT; ++i) {
        int c = tid * PT + i;
        vals[i] = (c < CC) ? counts[c] : 0;
        tot += vals[i];
    }
    __shared__ int sh[256];
    sh[tid] = tot;
    __syncthreads();
    for (int ofs = 1; ofs < 256; ofs <<= 1) {
        int v = (tid >= ofs) ? sh[tid - ofs] : 0;
        __syncthreads();
        sh[tid] += v;
        __syncthreads();
    }
    int run = sh[tid] - tot;
    #pragma unroll
    for (int i = 0; i < PT; ++i) {
        int c = tid * PT + i;
        if (c < CC) { offsets[c] = run; cursor[c] = run; }
        run += vals[i];
    }
}

// ---------------- fused scatter + f32->bf16 feature conversion ----------------
// 8 lanes per bank row: leader atomically claims the class-sorted slot p, then the
// 8 lanes copy the 1KB f32 row as 512B bf16 to featbf[p]. featbf ends up holding
// the features in class-sorted row order -> class_mfma staging is CONTIGUOUS.
__global__ __launch_bounds__(256) void scatter_conv(
    const int* __restrict__ labels, int* __restrict__ cursor,
    const float* __restrict__ features, unsigned short* __restrict__ featbf)
{
    int t = blockIdx.x * 256 + threadIdx.x;
    int n = t >> 3;        // bank row
    int g = t & 7;         // lane within row-group
    if (n >= NN) return;
    int c = labels[n];
    int p = 0;
    if (g == 0) p = atomicAdd(&cursor[c], 1);
    p = __shfl(p, (threadIdx.x & 63) & ~7, 64);   // broadcast leader's slot

    const float4* src = (const float4*)(features + (size_t)n * DD) + g * 8; // 128 B
    unsigned short* dst = featbf + (size_t)p * 256 + g * 32;                // 64 B
    #pragma unroll
    for (int i = 0; i < 4; ++i) {
        float4 a = src[2 * i], b = src[2 * i + 1];
        *(u16x8*)(dst + i * 8) = pack8(a, b);
    }
}

// ---------------- heavy kernel: persistent, global_load_lds staged, 2 blocks/CU ----------------
// Grid = GPERS x 512 threads (8 waves). Block walks classes c = bid, bid+GPERS, ...
// A-tile staged DIRECTLY from class-sorted bf16 featbf via global_load_lds (16B,
// wave-uniform LDS base + lane*16). LDS layout = fragment order: fragment f=(ma,kc)
// is a contiguous 1KB; chunk c of fragment (ma,kc) holds row 16*ma+((c&15)^kc),
// k-slice (c>>4). Source address pre-applies the XOR so dest stays linear (both-
// sides-or-neither). Read side identical to r7 (0 bank conflicts measured).
// No register staging, no convert VALU -> ~112 unified regs -> launch_bounds(512,4)
// holds without spill and 2 blocks/CU co-reside.
// Wave w: batch cols [32w,+32) (w<4 inputs: sum+max+min; w>=4 inputs2: sum).
// Partial tiles load the NEXT class's rows -> fold guards sum/max/min by validity.
// Stats transposed [col][CC] for coalesced finalize.
__global__ __launch_bounds__(512, 4) void class_mfma(
    const unsigned short* __restrict__ featbf, const unsigned short* __restrict__ inb,
    const int* __restrict__ offsets, const int* __restrict__ counts,
    float* __restrict__ gsumA, float* __restrict__ gsumB,
    float* __restrict__ gmax, float* __restrict__ gmin)
{
    const int tid = threadIdx.x;
    const int w   = tid >> 6;
    const int l   = tid & 63;

    __shared__ __align__(16) char lds[2][32768]; // double-buffered A tile (bf16, fragment order)

    // hoist B (input) fragments: kc 0..7, nb 0..1 -> 16 x bf16x8 (64 VGPR)
    bf16x8 bfr[16];
    #pragma unroll
    for (int kc = 0; kc < 8; ++kc)
        #pragma unroll
        for (int nb = 0; nb < 2; ++nb) {
            int nr = 2 * w + nb;
            bfr[kc * 2 + nb] = *(const bf16x8*)(inb + (((size_t)(nr * 8 + kc) * 64 + l) << 3));
        }

    // per-wave staging constants: 4 fragments f = 4w..4w+3, lane l sources the
    // chunk it will own linearly (dest = frag base + l*16, HW-applied).
    // chunk l of frag (ma,kc) holds row 16*ma + ((l&15)^kc), bytes kc*64+(l>>4)*16.
    const char* fb = (const char*)featbf;

    // ---- tile iterator state (wave-uniform) ----
    int cc = blockIdx.x;
    int ccnt = counts[cc], coff = offsets[cc];
    int cbase = 0;

    int nc = cc, ncnt = ccnt, noff = coff, nbase = 64;
    if (nbase >= ncnt) {
        nc = cc + GPERS; nbase = 0;
        if (nc < CC) { ncnt = counts[nc]; noff = offsets[nc]; }
    }

    // ---- prologue: stage tile 0 into lds[0] ----
    #pragma unroll
    for (int i = 0; i < 4; ++i) {
        int f  = w * 4 + i;
        int kc = f & 7;
        int row = 16 * (f >> 3) + ((l & 15) ^ kc);
        const char* src = fb + (((size_t)(coff + row)) << 9) + (kc << 6) + ((l >> 4) << 4);
        __builtin_amdgcn_global_load_lds(
            (const __attribute__((address_space(1))) void*)src,
            (__attribute__((address_space(3))) void*)(&lds[0][0] + (f << 10)),
            16, 0, 0);
    }
    __syncthreads();

    float s_sum[2] = {0.f, 0.f};
    float s_max[2] = {-3.4e38f, -3.4e38f};
    float s_min[2] = { 3.4e38f,  3.4e38f};

    int buf = 0;

    while (cc < CC) {
        const bool have_n = (nc < CC);

        // (1) issue async stage of next tile into lds[buf^1]
        if (have_n) {
            #pragma unroll
            for (int i = 0; i < 4; ++i) {
                int f  = w * 4 + i;
                int kc = f & 7;
                int row = 16 * (f >> 3) + ((l & 15) ^ kc);
                const char* src = fb + (((size_t)(noff + nbase + row)) << 9) + (kc << 6) + ((l >> 4) << 4);
                __builtin_amdgcn_global_load_lds(
                    (const __attribute__((address_space(1))) void*)src,
                    (__attribute__((address_space(3))) void*)(&lds[buf ^ 1][0] + (f << 10)),
                    16, 0, 0);
            }
        }

        // (2) advance to after-next tile
        int ac = nc, acnt = ncnt, aoff = noff, abase = nbase + 64;
        if (have_n && abase >= acnt) {
            ac = nc + GPERS; abase = 0;
            if (ac < CC) { acnt = counts[ac]; aoff = offsets[ac]; }
        }

        // (3) MFMA current tile from lds[buf]
        f32x4 acc[4][2];
        #pragma unroll
        for (int ma = 0; ma < 4; ++ma)
            #pragma unroll
            for (int nb = 0; nb < 2; ++nb)
                acc[ma][nb] = (f32x4){0.f, 0.f, 0.f, 0.f};

        __builtin_amdgcn_s_setprio(1);
        #pragma unroll
        for (int kc = 0; kc < 8; ++kc) {
            int lx = (l ^ kc) << 4;
            #pragma unroll
            for (int mah = 0; mah < 2; ++mah) {
                bf16x8 a0 = *(const bf16x8*)(&lds[buf][0] + (((2 * mah) * 8 + kc) << 10) + lx);
                bf16x8 a1 = *(const bf16x8*)(&lds[buf][0] + (((2 * mah + 1) * 8 + kc) << 10) + lx);
                acc[2 * mah][0] = __builtin_amdgcn_mfma_f32_16x16x32_bf16(a0, bfr[kc * 2 + 0], acc[2 * mah][0], 0, 0, 0);
                acc[2 * mah][1] = __builtin_amdgcn_mfma_f32_16x16x32_bf16(a0, bfr[kc * 2 + 1], acc[2 * mah][1], 0, 0, 0);
                acc[2 * mah + 1][0] = __builtin_amdgcn_mfma_f32_16x16x32_bf16(a1, bfr[kc * 2 + 0], acc[2 * mah + 1][0], 0, 0, 0);
                acc[2 * mah + 1][1] = __builtin_amdgcn_mfma_f32_16x16x32_bf16(a1, bfr[kc * 2 + 1], acc[2 * mah + 1][1], 0, 0, 0);
            }
        }
        __builtin_amdgcn_s_setprio(0);

        // (4) fold tile into running stats (partial tiles: guard EVERYTHING —
        //     padded lanes hold the next class's real data)
        const bool last = (cbase + 64 >= ccnt);
        if (cbase + 64 <= ccnt) {
            #pragma unroll
            for (int ma = 0; ma < 4; ++ma)
                #pragma unroll
                for (int reg = 0; reg < 4; ++reg)
                    #pragma unroll
                    for (int nb = 0; nb < 2; ++nb) {
                        float v = acc[ma][nb][reg];
                        s_sum[nb] += v;
                        if (w < 4) {
                            s_max[nb] = fmaxf(s_max[nb], v);
                            s_min[nb] = fminf(s_min[nb], v);
                        }
                    }
        } else {
            int mb = cbase + 4 * (l >> 4);
            #pragma unroll
            for (int ma = 0; ma < 4; ++ma)
                #pragma unroll
                for (int reg = 0; reg < 4; ++reg) {
                    bool valid = (mb + 16 * ma + reg) < ccnt;
                    #pragma unroll
                    for (int nb = 0; nb < 2; ++nb) {
                        float v = acc[ma][nb][reg];
                        if (valid) {
                            s_sum[nb] += v;
                            if (w < 4) {
                                s_max[nb] = fmaxf(s_max[nb], v);
                                s_min[nb] = fminf(s_min[nb], v);
                            }
                        }
                    }
                }
        }

        // class end: combine + write stats, reset
        if (last) {
            #pragma unroll
            for (int nb = 0; nb < 2; ++nb) {
                s_sum[nb] *= INVTEMP;
                s_sum[nb] += __shfl_xor(s_sum[nb], 16);
                s_sum[nb] += __shfl_xor(s_sum[nb], 32);
                if (w < 4) {
                    s_max[nb] *= INVTEMP;
                    s_min[nb] *= INVTEMP;
                    s_max[nb] = fmaxf(s_max[nb], __shfl_xor(s_max[nb], 16));
                    s_max[nb] = fmaxf(s_max[nb], __shfl_xor(s_max[nb], 32));
                    s_min[nb] = fminf(s_min[nb], __shfl_xor(s_min[nb], 16));
                    s_min[nb] = fminf(s_min[nb], __shfl_xor(s_min[nb], 32));
                }
            }
            if (l < 16) {
                #pragma unroll
                for (int nb = 0; nb < 2; ++nb) {
                    if (w < 4) {
                        int col = 32 * w + 16 * nb + l; // 0..127 (inputs)
                        gsumA[(size_t)col * CC + cc] = s_sum[nb];
                        gmax[(size_t)col * CC + cc]  = s_max[nb];
                        gmin[(size_t)col * CC + cc]  = s_min[nb];
                    } else {
                        int col = 32 * (w - 4) + 16 * nb + l; // 0..127 (inputs2)
                        gsumB[(size_t)col * CC + cc] = s_sum[nb];
                    }
                }
            }
            s_sum[0] = s_sum[1] = 0.f;
            s_max[0] = s_max[1] = -3.4e38f;
            s_min[0] = s_min[1] =  3.4e38f;
        }

        // (5) barrier: compiler drains vmcnt (global_load_lds) + lgkm before s_barrier
        __syncthreads();

        // (6) shift pipeline
        cc = nc; ccnt = ncnt; coff = noff; cbase = nbase;
        nc = ac; ncnt = acnt; noff = aoff; nbase = abase;
        buf ^= 1;
    }
}

// ---------------- finalize: losses ----------------

__device__ __forceinline__ float blk_reduce_sum(float v) {
    __shared__ float sh[4];
    int lane = threadIdx.x & 63, w = threadIdx.x >> 6;
    #pragma unroll
    for (int o = 32; o; o >>= 1) v += __shfl_down(v, o, 64);
    __syncthreads();
    if (lane == 0) sh[w] = v;
    __syncthreads();
    return sh[0] + sh[1] + sh[2] + sh[3];
}

__device__ __forceinline__ float blk_reduce_max(float v) {
    __shared__ float sh[4];
    int lane = threadIdx.x & 63, w = threadIdx.x >> 6;
    #pragma unroll
    for (int o = 32; o; o >>= 1) v = fmaxf(v, __shfl_down(v, o, 64));
    __syncthreads();
    if (lane == 0) sh[w] = v;
    __syncthreads();
    return fmaxf(fmaxf(sh[0], sh[1]), fmaxf(sh[2], sh[3]));
}

__global__ __launch_bounds__(256) void finalize_kernel(
    const float* __restrict__ gsumA, const float* __restrict__ gsumB,
    const float* __restrict__ gmax, const float* __restrict__ gmin,
    const int* __restrict__ counts, const int* __restrict__ labels,
    const int* __restrict__ indexes, float* __restrict__ out)
{
    const int b   = blockIdx.x;
    const int tid = threadIdx.x;
    const int tgt = labels[indexes[b]];

    __shared__ float sh_etgt;
    float local = 0.f;
    for (int c = tid; c < CC; c += 256) {
        float v = (c == tgt) ? gmin[(size_t)b * CC + c] : gmax[(size_t)b * CC + c];
        float e = (counts[c] > 0) ? expf(v) : 0.f;
        local += e;
        if (c == tgt) sh_etgt = e;
    }
    float sum_e = blk_reduce_sum(local);
    float etgt = sh_etgt;
    float loss_con_b = -logf(etgt / (sum_e + EPSV) + EPSV);

    __shared__ float a1[SS], a2[SS];
    for (int c = tid; c < SS; c += 256) {
        int n = counts[c];
        float icnt = 1.f / (float)(n > 0 ? n : 1);
        a1[c] = gsumA[(size_t)b * CC + c] * icnt;
        a2[c] = gsumB[(size_t)b * CC + c] * icnt;
    }
    __syncthreads();
    float m1 = -3.4e38f, m2 = -3.4e38f;
    for (int c = tid; c < SS; c += 256) { m1 = fmaxf(m1, a1[c]); m2 = fmaxf(m2, a2[c]); }
    m1 = blk_reduce_max(m1);
    m2 = blk_reduce_max(m2);
    float s1 = 0.f, s2 = 0.f;
    for (int c = tid; c < SS; c += 256) { s1 += expf(a1[c] - m1); s2 += expf(a2[c] - m2); }
    s1 = blk_reduce_sum(s1);
    s2 = blk_reduce_sum(s2);
    float inv1 = 1.f / s1, inv2 = 1.f / s2;
    float dsum = 0.f;
    for (int c = tid; c < SS; c += 256) {
        float d = expf(a1[c] - m1) * inv1 - expf(a2[c] - m2) * inv2;
        dsum += d * d;
    }
    dsum = blk_reduce_sum(dsum);
    if (tid == 0) {
        atomicAdd(&out[0], loss_con_b * (1.0f / (float)BB));
        atomicAdd(&out[1], dsum * (1.0f / (float)SS));
    }
}

// ---------------- launch ----------------

extern "C" void kernel_launch(void* const* d_in, const int* in_sizes, int n_in,
                              void* d_out, int out_size, void* d_ws, size_t ws_size,
                              hipStream_t stream) {
    const float* inputs   = (const float*)d_in[0];
    const float* inputs2  = (const float*)d_in[1];
    const float* features = (const float*)d_in[2];
    const int*   labels   = (const int*)d_in[3];
    const int*   indexes  = (const int*)d_in[4];

    float* out = (float*)d_out;

    // workspace layout
    int* wsi     = (int*)d_ws;
    int* counts  = wsi;            // [0, 2048)
    int* offsets = wsi + 2048;     // [2048, 4096)
    int* cursor  = wsi + 4096;     // [4096, 6144)
    unsigned short* inb    = (unsigned short*)(wsi + 6144);   // 65536 ushorts = 128 KB
    unsigned short* featbf = (unsigned short*)(wsi + 38912);  // NN*256 ushorts = 51.2 MB
    float* gsumA = (float*)d_ws + 12838912;                   // [128][CC] each (after featbf)
    float* gsumB = gsumA + CC * BB;
    float* gmaxp = gsumB + CC * BB;
    float* gminp = gmaxp + CC * BB;

    hipMemsetAsync(counts, 0, 2048 * sizeof(int), stream);

    hist_prep_kernel<<<HIST_BLOCKS + PREP_BLOCKS, 256, 0, stream>>>(
        labels, counts, inputs, inputs2, inb);
    scan_kernel<<<1, 256, 0, stream>>>(counts, offsets, cursor, out);
    scatter_conv<<<(NN * 8 + 255) / 256, 256, 0, stream>>>(labels, cursor, features, featbf);
    class_mfma<<<GPERS, 512, 0, stream>>>(featbf, inb, offsets, counts,
                                          gsumA, gsumB, gmaxp, gminp);
    finalize_kernel<<<BB, 256, 0, stream>>>(gsumA, gsumB, gmaxp, gminp, counts,
                                            labels, indexes, out);
}